// Round 1
// baseline (6932.343 us; speedup 1.0000x reference)
//
#include <hip/hip_runtime.h>
#include <hip/hip_bf16.h>
#include <math.h>

// MiniGPT forward: V=32000 E=1024 H=16 L=8 T=1024 B=4, D=64. Rows M = B*T = 4096.
// All matmuls are x @ W^T with W row-major [N,K] -> "B^T input" m97-style MFMA GEMM.

#define EDIM 1024
#define TDIM 1024
#define MROWS 4096

typedef __attribute__((ext_vector_type(8))) short short8;
typedef __attribute__((ext_vector_type(8))) __bf16 bf16x8;
typedef __attribute__((ext_vector_type(4))) float f32x4;

__device__ __forceinline__ unsigned short f2bf(float f) {
  unsigned u = __float_as_uint(f);
  u += 0x7fffu + ((u >> 16) & 1u);          // RNE
  return (unsigned short)(u >> 16);
}
__device__ __forceinline__ float bf2f(unsigned short s) {
  return __uint_as_float(((unsigned)s) << 16);
}

__device__ __forceinline__ void async16(const void* g, void* l) {
  __builtin_amdgcn_global_load_lds(
      (__attribute__((address_space(1))) void*)(void*)g,
      (__attribute__((address_space(3))) void*)l,
      16, 0, 0);
}

// ---------------- fp32 -> bf16 weight conversion ----------------
__global__ void cvt_kernel(const float* __restrict__ src, unsigned short* __restrict__ dst, int n4) {
  const int stride = gridDim.x * blockDim.x;
  for (int i = blockIdx.x * blockDim.x + threadIdx.x; i < n4; i += stride) {
    const float4 v = ((const float4*)src)[i];
    ushort4 o;
    o.x = f2bf(v.x); o.y = f2bf(v.y); o.z = f2bf(v.z); o.w = f2bf(v.w);
    ((ushort4*)dst)[i] = o;
  }
}

// ---------------- embedding: x = tok_emb[idx] + pos_emb ----------------
__global__ void embed_kernel(const int* __restrict__ idx, const float* __restrict__ tok,
                             const float* __restrict__ pos, float* __restrict__ x) {
  const int i = blockIdx.x * 256 + threadIdx.x;   // float4 index, total 4096*256 = 1048576
  const int row = i >> 8;                          // 256 float4 per row (E=1024)
  const int c4 = i & 255;
  const int tkn = idx[row];
  const int t = row & (TDIM - 1);
  float4 a = ((const float4*)tok)[(size_t)tkn * 256 + c4];
  const float4 p = ((const float4*)pos)[(size_t)t * 256 + c4];
  a.x += p.x; a.y += p.y; a.z += p.z; a.w += p.w;
  ((float4*)x)[i] = a;
}

// ---------------- LayerNorm (fp32 in, bf16 out), one wave per row ----------------
__global__ __launch_bounds__(256) void ln_kernel(const float* __restrict__ x,
                                                 const float* __restrict__ g,
                                                 const float* __restrict__ bta,
                                                 unsigned short* __restrict__ out) {
  const int lane = threadIdx.x & 63;
  const int wv = threadIdx.x >> 6;
  const size_t row = (size_t)blockIdx.x * 4 + wv;
  const float* xr = x + row * EDIM;
  float4 v[4];
  float s = 0.f, s2 = 0.f;
#pragma unroll
  for (int gi = 0; gi < 4; ++gi) {
    v[gi] = ((const float4*)xr)[gi * 64 + lane];
    s  += v[gi].x + v[gi].y + v[gi].z + v[gi].w;
    s2 += v[gi].x * v[gi].x + v[gi].y * v[gi].y + v[gi].z * v[gi].z + v[gi].w * v[gi].w;
  }
#pragma unroll
  for (int off = 1; off < 64; off <<= 1) {
    s  += __shfl_xor(s, off);
    s2 += __shfl_xor(s2, off);
  }
  const float mu = s * (1.f / 1024.f);
  const float rstd = rsqrtf(s2 * (1.f / 1024.f) - mu * mu + 1e-5f);
  unsigned short* orow = out + row * EDIM;
#pragma unroll
  for (int gi = 0; gi < 4; ++gi) {
    const int c = gi * 256 + lane * 4;
    const float4 gg = *(const float4*)(g + c);
    const float4 bb = *(const float4*)(bta + c);
    ushort4 o;
    o.x = f2bf((v[gi].x - mu) * rstd * gg.x + bb.x);
    o.y = f2bf((v[gi].y - mu) * rstd * gg.y + bb.y);
    o.z = f2bf((v[gi].z - mu) * rstd * gg.z + bb.z);
    o.w = f2bf((v[gi].w - mu) * rstd * gg.w + bb.w);
    *(ushort4*)(orow + c) = o;
  }
}

// ---------------- MFMA GEMM: C[M,N] = A[M,K](bf16) @ W[N,K]^T(bf16) ----------------
// MODE 0: store bf16 | 1: +bias, exact GELU, store bf16 | 2: fp32 C += acc
// MODE 3: fp32 C += acc + bias | 4: store fp32
template <int MODE>
__global__ __launch_bounds__(256) void gemm_bt(const unsigned short* __restrict__ A,
                                               const unsigned short* __restrict__ Bw,
                                               void* __restrict__ Cv,
                                               const float* __restrict__ bias,
                                               int K, int N) {
  __shared__ unsigned short As[128 * 64];
  __shared__ unsigned short Bs[128 * 64];
  const int tid = threadIdx.x;
  const int lane = tid & 63;
  const int wv = tid >> 6;
  const int wm = wv & 1, wn = wv >> 1;
  const int row_l = lane & 15, quad = lane >> 4;
  const size_t mBase = (size_t)blockIdx.y * 128;
  const size_t nBase = (size_t)blockIdx.x * 128;

  f32x4 acc[4][4];
#pragma unroll
  for (int i = 0; i < 4; ++i)
#pragma unroll
    for (int j = 0; j < 4; ++j) acc[i][j] = (f32x4){0.f, 0.f, 0.f, 0.f};

  for (int k0 = 0; k0 < K; k0 += 64) {
    __syncthreads();
#pragma unroll
    for (int it = 0; it < 4; ++it) {
      const int cb = it * 256 + wv * 64;   // wave-uniform chunk base (16B chunks)
      const int c = cb + lane;
      const int r = c >> 3;
      const int kc = c & 7;
      async16(A  + (mBase + r) * K + k0 + kc * 8, &As[cb * 8]);
      async16(Bw + (nBase + r) * K + k0 + kc * 8, &Bs[cb * 8]);
    }
    __syncthreads();
#pragma unroll
    for (int kk = 0; kk < 64; kk += 32) {
      bf16x8 af[4], bfr[4];
#pragma unroll
      for (int mi = 0; mi < 4; ++mi)
        af[mi] = *(const bf16x8*)&As[(wm * 64 + mi * 16 + row_l) * 64 + kk + quad * 8];
#pragma unroll
      for (int ni = 0; ni < 4; ++ni)
        bfr[ni] = *(const bf16x8*)&Bs[(wn * 64 + ni * 16 + row_l) * 64 + kk + quad * 8];
#pragma unroll
      for (int mi = 0; mi < 4; ++mi)
#pragma unroll
        for (int ni = 0; ni < 4; ++ni)
          acc[mi][ni] = __builtin_amdgcn_mfma_f32_16x16x32_bf16(af[mi], bfr[ni], acc[mi][ni], 0, 0, 0);
    }
  }

#pragma unroll
  for (int mi = 0; mi < 4; ++mi) {
#pragma unroll
    for (int ni = 0; ni < 4; ++ni) {
      const size_t col = nBase + wn * 64 + ni * 16 + row_l;
      const size_t row0 = mBase + wm * 64 + mi * 16 + quad * 4;
      const f32x4 a = acc[mi][ni];
#pragma unroll
      for (int r2 = 0; r2 < 4; ++r2) {
        const size_t off = (row0 + r2) * (size_t)N + col;
        float v = a[r2];
        if constexpr (MODE == 0) {
          ((unsigned short*)Cv)[off] = f2bf(v);
        } else if constexpr (MODE == 1) {
          v += bias[col];
          v = 0.5f * v * (1.f + erff(v * 0.70710678118f));
          ((unsigned short*)Cv)[off] = f2bf(v);
        } else if constexpr (MODE == 2) {
          ((float*)Cv)[off] += v;
        } else if constexpr (MODE == 3) {
          ((float*)Cv)[off] += v + bias[col];
        } else {
          ((float*)Cv)[off] = v;
        }
      }
    }
  }
}

// ---------------- flash attention (fp32 VALU), causal ----------------
// block = one (b, h, 64-row Q tile); 4 threads per Q row, 16 dims each.
__global__ __launch_bounds__(256) void attn_kernel(const unsigned short* __restrict__ qkv,
                                                   unsigned short* __restrict__ y) {
  __shared__ float Ks[64 * 64];
  __shared__ float Vs[64 * 64];
  const int tid = threadIdx.x;
  const int lane = tid & 63, wv = tid >> 6;
  const int rloc = lane & 15, quad = lane >> 4;
  const int bid = blockIdx.x;
  const int qt = bid & 15;
  const int bh = bid >> 4;
  const int h = bh & 15, b = bh >> 4;
  const int t = qt * 64 + wv * 16 + rloc;
  const int d0 = quad * 16;

  const float SCL = 0.125f * 1.44269504089f;  // 1/sqrt(64) * log2(e)
  float q[16];
  {
    const unsigned short* qp = qkv + ((size_t)(b * TDIM + t)) * 3072 + h * 64 + d0;
    const short8 q0 = *(const short8*)qp;
    const short8 q1 = *(const short8*)(qp + 8);
#pragma unroll
    for (int j = 0; j < 8; ++j) {
      q[j]     = bf2f((unsigned short)q0[j]) * SCL;
      q[8 + j] = bf2f((unsigned short)q1[j]) * SCL;
    }
  }
  float o[16];
#pragma unroll
  for (int j = 0; j < 16; ++j) o[j] = 0.f;
  float m = -1e30f, l = 0.f;

  for (int s0 = 0; s0 <= qt * 64; s0 += 64) {
    __syncthreads();
#pragma unroll
    for (int p = 0; p < 2; ++p) {
      const int sr = p * 32 + (tid >> 3);
      const int c8 = (tid & 7) * 8;
      const unsigned short* kp = qkv + ((size_t)(b * TDIM + s0 + sr)) * 3072 + 1024 + h * 64 + c8;
      const short8 kv = *(const short8*)kp;
      const short8 vv = *(const short8*)(kp + 1024);
#pragma unroll
      for (int e = 0; e < 8; ++e) {
        Ks[sr * 64 + c8 + e] = bf2f((unsigned short)kv[e]);
        Vs[sr * 64 + c8 + e] = bf2f((unsigned short)vv[e]);
      }
    }
    __syncthreads();
    for (int s = 0; s < 64; ++s) {
      const float4 k0 = *(const float4*)&Ks[s * 64 + d0];
      const float4 k1 = *(const float4*)&Ks[s * 64 + d0 + 4];
      const float4 k2 = *(const float4*)&Ks[s * 64 + d0 + 8];
      const float4 k3 = *(const float4*)&Ks[s * 64 + d0 + 12];
      float part = q[0] * k0.x + q[1] * k0.y + q[2] * k0.z + q[3] * k0.w
                 + q[4] * k1.x + q[5] * k1.y + q[6] * k1.z + q[7] * k1.w
                 + q[8] * k2.x + q[9] * k2.y + q[10] * k2.z + q[11] * k2.w
                 + q[12] * k3.x + q[13] * k3.y + q[14] * k3.z + q[15] * k3.w;
      part += __shfl_xor(part, 16);
      part += __shfl_xor(part, 32);
      const float sc = (s0 + s <= t) ? part : -1e30f;
      const float mn = fmaxf(m, sc);
      if (mn > m) {
        const float alpha = exp2f(m - mn);
        l *= alpha;
#pragma unroll
        for (int j = 0; j < 16; ++j) o[j] *= alpha;
        m = mn;
      }
      const float p = exp2f(sc - m);
      l += p;
      const float4 v0 = *(const float4*)&Vs[s * 64 + d0];
      const float4 v1 = *(const float4*)&Vs[s * 64 + d0 + 4];
      const float4 v2 = *(const float4*)&Vs[s * 64 + d0 + 8];
      const float4 v3 = *(const float4*)&Vs[s * 64 + d0 + 12];
      o[0] += p * v0.x; o[1] += p * v0.y; o[2]  += p * v0.z; o[3]  += p * v0.w;
      o[4] += p * v1.x; o[5] += p * v1.y; o[6]  += p * v1.z; o[7]  += p * v1.w;
      o[8] += p * v2.x; o[9] += p * v2.y; o[10] += p * v2.z; o[11] += p * v2.w;
      o[12] += p * v3.x; o[13] += p * v3.y; o[14] += p * v3.z; o[15] += p * v3.w;
    }
  }
  const float inv = 1.f / l;
  short8 r0, r1;
#pragma unroll
  for (int j = 0; j < 8; ++j) {
    r0[j] = (short)f2bf(o[j] * inv);
    r1[j] = (short)f2bf(o[8 + j] * inv);
  }
  unsigned short* yp = y + ((size_t)(b * TDIM + t)) * 1024 + h * 64 + d0;
  *(short8*)yp = r0;
  *(short8*)(yp + 8) = r1;
}

// ---------------- host ----------------
extern "C" void kernel_launch(void* const* d_in, const int* in_sizes, int n_in,
                              void* d_out, int out_size, void* d_ws, size_t ws_size,
                              hipStream_t stream) {
  const int*   idx    = (const int*)  d_in[0];
  const float* tok    = (const float*)d_in[1];
  const float* pos    = (const float*)d_in[2];
  const float* qkv_w  = (const float*)d_in[3];
  const float* proj_w = (const float*)d_in[4];
  const float* ln1_g  = (const float*)d_in[5];
  const float* ln1_b  = (const float*)d_in[6];
  const float* ln2_g  = (const float*)d_in[7];
  const float* ln2_b  = (const float*)d_in[8];
  const float* fc1_w  = (const float*)d_in[9];
  const float* fc1_b  = (const float*)d_in[10];
  const float* fc2_w  = (const float*)d_in[11];
  const float* fc2_b  = (const float*)d_in[12];
  const float* lnf_g  = (const float*)d_in[13];
  const float* lnf_b  = (const float*)d_in[14];
  const float* head_w = (const float*)d_in[15];

  char* ws = (char*)d_ws;
  unsigned short* wq   = (unsigned short*)(ws + 0);           // 25165824 bf16
  unsigned short* wp   = (unsigned short*)(ws + 50331648);    //  8388608 bf16
  unsigned short* w1   = (unsigned short*)(ws + 67108864);    // 33554432 bf16
  unsigned short* w2   = (unsigned short*)(ws + 134217728);   // 33554432 bf16
  unsigned short* wh   = (unsigned short*)(ws + 201326592);   // 32768000 bf16
  float*          x    = (float*)         (ws + 266862592);   //  4194304 f32
  unsigned short* hbuf = (unsigned short*)(ws + 283639808);   //  4194304 bf16
  unsigned short* qkvb = (unsigned short*)(ws + 292028416);   // 12582912 bf16
  unsigned short* ybuf = (unsigned short*)(ws + 317194240);   //  4194304 bf16
  unsigned short* mid  = (unsigned short*)(ws + 325582848);   // 16777216 bf16

  cvt_kernel<<<4096, 256, 0, stream>>>(qkv_w,  wq, 25165824 / 4);
  cvt_kernel<<<4096, 256, 0, stream>>>(proj_w, wp,  8388608 / 4);
  cvt_kernel<<<4096, 256, 0, stream>>>(fc1_w,  w1, 33554432 / 4);
  cvt_kernel<<<4096, 256, 0, stream>>>(fc2_w,  w2, 33554432 / 4);
  cvt_kernel<<<4096, 256, 0, stream>>>(head_w, wh, 32768000 / 4);

  embed_kernel<<<4096, 256, 0, stream>>>(idx, tok, pos, x);

  for (int l = 0; l < 8; ++l) {
    ln_kernel<<<1024, 256, 0, stream>>>(x, ln1_g + l * 1024, ln1_b + l * 1024, hbuf);
    gemm_bt<0><<<dim3(24, 32), 256, 0, stream>>>(hbuf, wq + (size_t)l * 3145728, qkvb, nullptr, 1024, 3072);
    attn_kernel<<<1024, 256, 0, stream>>>(qkvb, ybuf);
    gemm_bt<2><<<dim3(8, 32), 256, 0, stream>>>(ybuf, wp + (size_t)l * 1048576, x, nullptr, 1024, 1024);
    ln_kernel<<<1024, 256, 0, stream>>>(x, ln2_g + l * 1024, ln2_b + l * 1024, hbuf);
    gemm_bt<1><<<dim3(32, 32), 256, 0, stream>>>(hbuf, w1 + (size_t)l * 4194304, mid, fc1_b + l * 4096, 1024, 4096);
    gemm_bt<3><<<dim3(8, 32), 256, 0, stream>>>(mid, w2 + (size_t)l * 4194304, x, fc2_b + l * 1024, 4096, 1024);
  }
  ln_kernel<<<1024, 256, 0, stream>>>(x, lnf_g, lnf_b, hbuf);
  gemm_bt<4><<<dim3(250, 32), 256, 0, stream>>>(hbuf, wh, d_out, nullptr, 1024, 32000);
}